// Round 10
// baseline (151.679 us; speedup 1.0000x reference)
//
#include <hip/hip_runtime.h>
#include <math.h>

static constexpr float kSigma = 3.5412f;
static constexpr float kMu    = -9.1232f;

// ---------- compile-time twiddles: cos / -sin of 2*pi*k/n (constexpr Taylor) ----------
constexpr double kPId = 3.14159265358979323846264338327950288;

constexpr double tp_sin(double r) {
    const double r2 = r * r;
    double t = r, s = r;
    t *= -r2 / (2.0 * 3.0);   s += t;
    t *= -r2 / (4.0 * 5.0);   s += t;
    t *= -r2 / (6.0 * 7.0);   s += t;
    t *= -r2 / (8.0 * 9.0);   s += t;
    t *= -r2 / (10.0 * 11.0); s += t;
    t *= -r2 / (12.0 * 13.0); s += t;
    return s;
}
constexpr double tp_cos(double r) {
    const double r2 = r * r;
    double t = 1.0, c = 1.0;
    t *= -r2 / (1.0 * 2.0);   c += t;
    t *= -r2 / (3.0 * 4.0);   c += t;
    t *= -r2 / (5.0 * 6.0);   c += t;
    t *= -r2 / (7.0 * 8.0);   c += t;
    t *= -r2 / (9.0 * 10.0);  c += t;
    t *= -r2 / (11.0 * 12.0); c += t;
    return c;
}
constexpr float ctw_c(int k, int n) {
    const int kk = ((k % n) + n) % n;
    const int q = (4 * kk) / n;
    const int num = 4 * kk - q * n;
    const double r = (2.0 * kPId * num) / (4.0 * n);
    const double cr = tp_cos(r), sr = tp_sin(r);
    return (float)(q == 0 ? cr : q == 1 ? -sr : q == 2 ? -cr : sr);
}
constexpr float ctw_ns(int k, int n) {
    const int kk = ((k % n) + n) % n;
    const int q = (4 * kk) / n;
    const int num = 4 * kk - q * n;
    const double r = (2.0 * kPId * num) / (4.0 * n);
    const double cr = tp_cos(r), sr = tp_sin(r);
    const double s = (q == 0 ? sr : q == 1 ? cr : q == 2 ? -sr : -cr);
    return (float)(-s);
}

// pair-exchange (even<->odd lane) via DPP quad_perm(1,0,3,2): pure VALU, no DS pipe
__device__ __forceinline__ float pair_swap(float v) {
    return __int_as_float(__builtin_amdgcn_mov_dpp(__float_as_int(v), 0xB1, 0xF, 0xF, true));
}

// padded LDS index: one pad float per 32. For seg bases B with B % 32 == 0,
// (B + c) maps to (B + B/32) + KA(c) EXACTLY -> compile-time c folds into
// ds_read offset immediates.
#define KA(c) ((c) + ((c) >> 5))

// ---------- named-scalar Z state (ONE signal per lane): names 0..11 = bins BSTART-1..BSTART+10
#define DECLZ \
    float zr0=0.f,zi0=0.f, zr1=0.f,zi1=0.f, zr2=0.f,zi2=0.f, zr3=0.f,zi3=0.f, \
          zr4=0.f,zi4=0.f, zr5=0.f,zi5=0.f, zr6=0.f,zi6=0.f, zr7=0.f,zi7=0.f, \
          zr8=0.f,zi8=0.f, zr9=0.f,zi9=0.f, zr10=0.f,zi10=0.f, zr11=0.f,zi11=0.f; \
    (void)zr0;(void)zi0;(void)zr11;(void)zi11;

// one bin update at (state name n, sample m): Z += d * omega^{b(m+TAU*H)}
#define UPDB(n, m) \
    if constexpr ((n) >= 1 && (n) <= NB) { \
        constexpr int   k_ = (BSTART + (n) - 1) * ((m) + TAU * HH); \
        constexpr float c_ = ctw_c(k_, NN); \
        constexpr float s_ = ctw_ns(k_, NN); \
        zr##n = fmaf(d, c_, zr##n);  zi##n = fmaf(d, s_, zi##n); \
    }

#define ALLB(m) UPDB(1,m) UPDB(2,m) UPDB(3,m) UPDB(4,m) UPDB(5,m) \
                UPDB(6,m) UPDB(7,m) UPDB(8,m) UPDB(9,m) UPDB(10,m)

// main-loop sample step (delta = new - old); all LDS offsets compile-time.
#define UPD_M(m) \
    if constexpr ((m) < HH) { \
        const float d = psb[KA(QB + TAU*HH + NN + (m))] - psb[KA(QB + TAU*HH + (m))]; \
        ALLB(m) \
        if constexpr (((m) & 7) == 7) __builtin_amdgcn_sched_barrier(0); \
    }
// warmup sample step: add-only (builds X_{t0} exactly)
#define WRM_M(m) \
    if constexpr ((m) < HH) { \
        const float d = psb[KA(OFF + TAU*HH + (m))]; \
        ALLB(m) \
        if constexpr (((m) & 7) == 7) __builtin_amdgcn_sched_barrier(0); \
    }

#define FORM(M) M(0) M(1) M(2) M(3) M(4) M(5) M(6) M(7) \
                M(8) M(9) M(10) M(11) M(12) M(13) M(14) M(15)

// emit one bin. Each lane computes ONLY its own signal's sqrt/log; the pair
// exchanges mag/lg via DPP quad_perm. sd2/slg symmetric-duplicated (2x true,
// folded in finalize); sy2 accumulates OWN mag^2, masked to sig==1 pre-reduce.
#define EMTB(nm, nc, np) \
    if constexpr (((nc) - 1) >= EJ0 && ((nc) - 1) < EJ0 + EN) { \
        constexpr int BG = BSTART + (nc) - 1; \
        float wr, wi; \
        if constexpr (BG == 0) { \
            const float s_ = (PH==0) ? zr##np : (PH==1) ? -zi##np : (PH==2) ? -zr##np : zi##np; \
            wr = 0.5f*zr##nc - 0.5f*s_;  wi = 0.5f*zi##nc; \
        } else if constexpr (BG == NN/2) { \
            const float s_ = (PH==0) ? zr##nm : (PH==1) ? zi##nm : (PH==2) ? -zr##nm : -zi##nm; \
            wr = 0.5f*zr##nc - 0.5f*s_;  wi = 0.5f*zi##nc; \
        } else { \
            const float tr = (PH==0) ? (zr##nm + zr##np) : (PH==1) ? (zi##nm - zi##np) \
                           : (PH==2) ? (-zr##nm - zr##np) : (zi##np - zi##nm); \
            const float ti = (PH==0) ? (zi##nm + zi##np) : (PH==1) ? (zr##np - zr##nm) \
                           : (PH==2) ? (-zi##nm - zi##np) : (zr##nm - zr##np); \
            wr = fmaf(-0.25f, tr, 0.5f*zr##nc);  wi = fmaf(-0.25f, ti, 0.5f*zi##nc); \
        } \
        const float pm   = fmaf(wr, wr, wi*wi); \
        const float mag  = sqrtf(pm) + 1e-7f; \
        const float lg   = __log2f(mag); \
        const float mago = pair_swap(mag); \
        const float lgo  = pair_swap(lg); \
        const float d_   = mag - mago; \
        sd2 = fmaf(d_, d_, sd2); \
        sy2 = fmaf(mag, mag, sy2); \
        slg += fabsf(lg - lgo); \
    }

#define FOREMT(M) M(0,1,2) M(1,2,3) M(2,3,4) M(3,4,5) M(4,5,6) \
                  M(5,6,7) M(6,7,8) M(7,8,9) M(8,9,10) M(9,10,11)

#define SLOT(q, t) { constexpr int QB = OFF + 4*HH*(q); constexpr int TAU = (t); \
                     constexpr int PH = (t); FOREMT(EMTB) FORM(UPD_M) }
#define SLOT4(q) SLOT(q,0) SLOT(q,1) SLOT(q,2) SLOT(q,3)
#define WARM(t) { constexpr int TAU = (t); FORM(WRM_M) }

// one (bin-group, frame-segment, signal) worker, fully unrolled.
// Seg bases B = t0*HH are ALL multiples of 32 (t0 = {8s,8s,8s,16s}; HH =
// {16,8,4,2}) -> padded addressing is exact with runtime base + const offsets.
template <int NN, int BSTART, int NB, int EJ0, int EN, int OFF, int LOG2SEGS>
__device__ __forceinline__ void run_group(const float* __restrict__ ps0,
                                          int seg, float& sd2, float& sy2, float& slg)
{
    constexpr int HH = NN / 4;
    constexpr int FF = 4096 / NN + 1;           // frames
    constexpr int NQ = FF >> (LOG2SEGS + 2);    // full quad-slots per segment
    static_assert(NQ == 2 || NQ == 4, "unroll pattern assumes NQ in {2,4}");
    const int t0 = (seg * FF) >> LOG2SEGS;
    const int t1 = ((seg + 1) * FF) >> LOG2SEGS;
    const int L  = t1 - t0;                     // 4*NQ or 4*NQ+1 (last seg only)
    const int B  = t0 * HH;                     // % 32 == 0 by construction
    const float* __restrict__ psb = ps0 + B + (B >> 5);

    DECLZ
    WARM(0) WARM(1) WARM(2) WARM(3)             // Z = X_{t0} exactly

    SLOT4(0) SLOT4(1)
    if constexpr (NQ == 4) { SLOT4(2) SLOT4(3) }
    if (L > 4 * NQ) { SLOT(NQ, 0) }             // rem is 0 or 1 by construction
}

// one resolution per kernel. Block = 256 threads = 4 waves, 4 rows x 2 sigs
// interleaved in one LDS array of 8 sequences. RSTR residues mod 32 chosen so
// (row-bank + seg-phase) tiles 32 banks <=2-way (n64: R=1/P=4, n32: R=9/P=2,
// n16/n8: R=8/P=1); 2-way is free.
template <int NN, int NGROUPS>
__global__ __launch_bounds__(256, 4)
void sdft_kernel(const float* __restrict__ xg, const float* __restrict__ yg,
                 float* __restrict__ acc /* this resolution: [0],[64],[128] */)
{
    constexpr int RSTR = (NN == 64) ? 1153 : (NN == 32) ? 1161 : 1160;
    __shared__ float lds[8][RSTR];              // seq = rr*2+sig; ~37 KB -> 4 blocks/CU
    __shared__ float red[4][3];

    const int tid  = threadIdx.x;
    const int row0 = blockIdx.x << 2;

    // ---- stage central 1024 samples/row/signal as float4 (staged j = 32 + i)
#pragma unroll 1
    for (int task = tid; task < 2048; task += 256) {
        const int q = task & 255, rr = (task >> 8) & 3, sg = task >> 10;
        const float* __restrict__ src = sg ? yg : xg;
        const float4 v = reinterpret_cast<const float4*>(src)[((row0 + rr) << 8) + q];
        const int j = 32 + (q << 2);            // j%4==0 -> quad never crosses pad
        float* dst = &lds[rr * 2 + sg][KA(j)];
        dst[0] = __expf(fmaf(v.x, kSigma, kMu));
        dst[1] = __expf(fmaf(v.y, kSigma, kMu));
        dst[2] = __expf(fmaf(v.z, kSigma, kMu));
        dst[3] = __expf(fmaf(v.w, kSigma, kMu));
    }
    // ---- reflect pads (32 each side) + zero tail [1088,1104)
#pragma unroll 1
    for (int task = tid; task < 640; task += 256) {
        const int p = task % 80, rem_ = task / 80;
        const int rr = rem_ & 3, sg = rem_ >> 2;
        const int j = (p < 32) ? p : (1024 + p);
        float v = 0.f;
        if (j < 1088) {
            const int i = (j < 32) ? (32 - j) : (2078 - j);
            const float* __restrict__ src = sg ? yg : xg;
            v = __expf(fmaf(src[((row0 + rr) << 10) + i], kSigma, kMu));
        }
        lds[rr * 2 + sg][KA(j)] = v;
    }
    __syncthreads();

    // ---- wave mapping: group = wid & (NGROUPS-1); remaining wave bits extend seg.
    //      64 lanes = seg(8) x row(4) x sig(2); pair lanes share (seg,row).
    constexpr int GL2 = (NGROUPS == 4) ? 2 : (NGROUPS == 2) ? 1 : 0;
    constexpr int LOG2SEGS = 5 - GL2;           // n64:8, n32:16, n16/n8:32 segments
    const int wid  = tid >> 6, lane = tid & 63;
    const int group  = wid & (NGROUPS - 1);
    const int segblk = wid >> GL2;
    const int seg  = (segblk << 3) | (lane >> 3);
    const int sig  = lane & 1;
    const float* ps0 = &lds[lane & 7][0];       // lane&7 == rr*2+sig

    float sd2 = 0.f, sy2 = 0.f, slg = 0.f;
    if constexpr (NN == 64) {
        switch (group) {
            case 0:  run_group<64,  0,  9, 0, 8,  0, LOG2SEGS>(ps0, seg, sd2, sy2, slg); break;
            case 1:  run_group<64,  7, 10, 1, 8,  0, LOG2SEGS>(ps0, seg, sd2, sy2, slg); break;
            case 2:  run_group<64, 15, 10, 1, 8,  0, LOG2SEGS>(ps0, seg, sd2, sy2, slg); break;
            default: run_group<64, 23, 10, 1, 9,  0, LOG2SEGS>(ps0, seg, sd2, sy2, slg); break;
        }
    } else if constexpr (NN == 32) {
        if (group == 0) run_group<32,  0,  9, 0, 8, 16, LOG2SEGS>(ps0, seg, sd2, sy2, slg);
        else            run_group<32,  7, 10, 1, 9, 16, LOG2SEGS>(ps0, seg, sd2, sy2, slg);
    } else if constexpr (NN == 16) {
        run_group<16, 0, 9, 0, 9, 24, LOG2SEGS>(ps0, seg, sd2, sy2, slg);
    } else {
        run_group< 8, 0, 5, 0, 5, 28, LOG2SEGS>(ps0, seg, sd2, sy2, slg);
    }

    // ---- reduce: mask sy2 to y-lanes, wave shuffle -> LDS -> 3 atomics/block
    if (!sig) sy2 = 0.f;
#pragma unroll
    for (int o = 32; o > 0; o >>= 1) {
        sd2 += __shfl_down(sd2, o);
        sy2 += __shfl_down(sy2, o);
        slg += __shfl_down(slg, o);
    }
    if (lane == 0) { red[wid][0] = sd2; red[wid][1] = sy2; red[wid][2] = slg; }
    __syncthreads();
    if (tid == 0) {
        atomicAdd(&acc[0],   red[0][0] + red[1][0] + red[2][0] + red[3][0]);
        atomicAdd(&acc[64],  red[0][1] + red[1][1] + red[2][1] + red[3][1]);
        atomicAdd(&acc[128], red[0][2] + red[1][2] + red[2][2] + red[3][2]);
    }
}

__global__ void finalize_kernel(const float* __restrict__ acc, float* __restrict__ out)
{
    if (threadIdx.x == 0 && blockIdx.x == 0) {
        const float nel[4] = {10506240.f, 9474048.f, 8982528.f, 8785920.f};
        float sc = 0.f, mg = 0.f;
#pragma unroll
        for (int r = 0; r < 4; ++r) {
            const float a0 = acc[(r * 3 + 0) * 64];   // 2x sum_d2
            const float a1 = acc[(r * 3 + 1) * 64];   // 1x sum_y2 (masked to y-lanes)
            const float a2 = acc[(r * 3 + 2) * 64];   // 2x sum_|log2 ratio|
            sc += sqrtf(a0 * 0.5f) / (sqrtf(a1) + 1e-8f);
            mg += a2 * 0.34657359028f / nel[r];       // x ln2 / 2
        }
        out[0] = sc * 0.25f;
        out[1] = mg * 0.25f;
    }
}

extern "C" void kernel_launch(void* const* d_in, const int* in_sizes, int n_in,
                              void* d_out, int out_size, void* d_ws, size_t ws_size,
                              hipStream_t stream)
{
    const float* x = (const float*)d_in[0];
    const float* y = (const float*)d_in[1];
    float* out = (float*)d_out;
    float* acc = (float*)d_ws;   // res r base = acc + r*192; r: 0=n8,1=n16,2=n32,3=n64

    hipMemsetAsync(acc, 0, 12 * 64 * sizeof(float), stream);

    sdft_kernel<64, 4><<<1024, 256, 0, stream>>>(x, y, acc + 3 * 192);
    sdft_kernel<32, 2><<<1024, 256, 0, stream>>>(x, y, acc + 2 * 192);
    sdft_kernel<16, 1><<<1024, 256, 0, stream>>>(x, y, acc + 1 * 192);
    sdft_kernel< 8, 1><<<1024, 256, 0, stream>>>(x, y, acc + 0 * 192);

    finalize_kernel<<<1, 64, 0, stream>>>(acc, out);
}

// Round 11
// 143.723 us; speedup vs baseline: 1.0554x; 1.0554x over previous
//
#include <hip/hip_runtime.h>
#include <math.h>

static constexpr float kSigma = 3.5412f;
static constexpr float kMu    = -9.1232f;

// ---------- compile-time twiddles: cos / -sin of 2*pi*k/n (constexpr Taylor) ----------
constexpr double kPId = 3.14159265358979323846264338327950288;

constexpr double tp_sin(double r) {
    const double r2 = r * r;
    double t = r, s = r;
    t *= -r2 / (2.0 * 3.0);   s += t;
    t *= -r2 / (4.0 * 5.0);   s += t;
    t *= -r2 / (6.0 * 7.0);   s += t;
    t *= -r2 / (8.0 * 9.0);   s += t;
    t *= -r2 / (10.0 * 11.0); s += t;
    t *= -r2 / (12.0 * 13.0); s += t;
    return s;
}
constexpr double tp_cos(double r) {
    const double r2 = r * r;
    double t = 1.0, c = 1.0;
    t *= -r2 / (1.0 * 2.0);   c += t;
    t *= -r2 / (3.0 * 4.0);   c += t;
    t *= -r2 / (5.0 * 6.0);   c += t;
    t *= -r2 / (7.0 * 8.0);   c += t;
    t *= -r2 / (9.0 * 10.0);  c += t;
    t *= -r2 / (11.0 * 12.0); c += t;
    return c;
}
constexpr float ctw_c(int k, int n) {
    const int kk = ((k % n) + n) % n;
    const int q = (4 * kk) / n;
    const int num = 4 * kk - q * n;
    const double r = (2.0 * kPId * num) / (4.0 * n);
    const double cr = tp_cos(r), sr = tp_sin(r);
    return (float)(q == 0 ? cr : q == 1 ? -sr : q == 2 ? -cr : sr);
}
constexpr float ctw_ns(int k, int n) {
    const int kk = ((k % n) + n) % n;
    const int q = (4 * kk) / n;
    const int num = 4 * kk - q * n;
    const double r = (2.0 * kPId * num) / (4.0 * n);
    const double cr = tp_cos(r), sr = tp_sin(r);
    const double s = (q == 0 ? sr : q == 1 ? cr : q == 2 ? -sr : -cr);
    return (float)(-s);
}

// pair-exchange (even<->odd lane) via DPP quad_perm(1,0,3,2): pure VALU, no DS pipe
__device__ __forceinline__ float pair_swap(float v) {
    return __int_as_float(__builtin_amdgcn_mov_dpp(__float_as_int(v), 0xB1, 0xF, 0xF, true));
}

// per-seq bank offset: exact 2-cover of 32 banks when combined with seg phase
// (2s for n64/n32/n16, 4s for n8). Verified by enumeration.
template <int NN>
constexpr int phi_seq(int q) {
    return (NN == 8) ? (((q & 1) << 4) + (q >> 1))                      // 0,16,1,17,2,18,3,19
                     : (((q & 1) << 4) + ((q >> 1) & 1) + ((q & 4) << 1)); // 0,16,1,17,8,24,9,25
}

// ---------- named-scalar Z state (ONE signal per lane): names 0..11 = bins BSTART-1..BSTART+10
#define DECLZ \
    float zr0=0.f,zi0=0.f, zr1=0.f,zi1=0.f, zr2=0.f,zi2=0.f, zr3=0.f,zi3=0.f, \
          zr4=0.f,zi4=0.f, zr5=0.f,zi5=0.f, zr6=0.f,zi6=0.f, zr7=0.f,zi7=0.f, \
          zr8=0.f,zi8=0.f, zr9=0.f,zi9=0.f, zr10=0.f,zi10=0.f, zr11=0.f,zi11=0.f; \
    (void)zr0;(void)zi0;(void)zr11;(void)zi11;

// one bin update at (state name n, sample m): Z += d * omega^{b(m+TAU*H)}
#define UPDB(n, m) \
    if constexpr ((n) >= 1 && (n) <= NB) { \
        constexpr int   k_ = (BSTART + (n) - 1) * ((m) + TAU * HH); \
        constexpr float c_ = ctw_c(k_, NN); \
        constexpr float s_ = ctw_ns(k_, NN); \
        zr##n = fmaf(d, c_, zr##n);  zi##n = fmaf(d, s_, zi##n); \
    }

#define ALLB(m) UPDB(1,m) UPDB(2,m) UPDB(3,m) UPDB(4,m) UPDB(5,m) \
                UPDB(6,m) UPDB(7,m) UPDB(8,m) UPDB(9,m) UPDB(10,m)

// padded const offset: pad period = NN floats; exact because B, off are
// multiples of NN -> (B+off+c) + ((B+off+c)>>LNN) splits termwise.
#define KAC(c) ((c) + ((c) >> LNN))

// main-loop sample step (delta = new - old); runtime offp (= off + off>>LNN)
// keeps the scheduler from hoisting all loads (round-10 spill lesson).
#define UPD_M(m) \
    if constexpr ((m) < HH) { \
        const float d = psb[offp + KAC(OFF + TAU*HH + NN + (m))] \
                      - psb[offp + KAC(OFF + TAU*HH + (m))]; \
        ALLB(m) \
        if constexpr (((m) & 7) == 7) __builtin_amdgcn_sched_barrier(0); \
    }
// warmup sample step: add-only (builds X_{t0} exactly)
#define WRM_M(m) \
    if constexpr ((m) < HH) { \
        const float d = psb[KAC(OFF + TAU*HH + (m))]; \
        ALLB(m) \
        if constexpr (((m) & 7) == 7) __builtin_amdgcn_sched_barrier(0); \
    }

#define FORM(M) M(0) M(1) M(2) M(3) M(4) M(5) M(6) M(7) \
                M(8) M(9) M(10) M(11) M(12) M(13) M(14) M(15)

// emit one bin. Each lane computes ONLY its own signal's sqrt/log; the pair
// exchanges mag/lg via DPP quad_perm. sd2/slg symmetric-duplicated (2x true,
// folded in finalize); sy2 accumulates OWN mag^2, masked to sig==1 pre-reduce.
#define EMTB(nm, nc, np) \
    if constexpr (((nc) - 1) >= EJ0 && ((nc) - 1) < EJ0 + EN) { \
        constexpr int BG = BSTART + (nc) - 1; \
        float wr, wi; \
        if constexpr (BG == 0) { \
            const float s_ = (PH==0) ? zr##np : (PH==1) ? -zi##np : (PH==2) ? -zr##np : zi##np; \
            wr = 0.5f*zr##nc - 0.5f*s_;  wi = 0.5f*zi##nc; \
        } else if constexpr (BG == NN/2) { \
            const float s_ = (PH==0) ? zr##nm : (PH==1) ? zi##nm : (PH==2) ? -zr##nm : -zi##nm; \
            wr = 0.5f*zr##nc - 0.5f*s_;  wi = 0.5f*zi##nc; \
        } else { \
            const float tr = (PH==0) ? (zr##nm + zr##np) : (PH==1) ? (zi##nm - zi##np) \
                           : (PH==2) ? (-zr##nm - zr##np) : (zi##np - zi##nm); \
            const float ti = (PH==0) ? (zi##nm + zi##np) : (PH==1) ? (zr##np - zr##nm) \
                           : (PH==2) ? (-zi##nm - zi##np) : (zr##nm - zr##np); \
            wr = fmaf(-0.25f, tr, 0.5f*zr##nc);  wi = fmaf(-0.25f, ti, 0.5f*zi##nc); \
        } \
        const float pm   = fmaf(wr, wr, wi*wi); \
        const float mag  = sqrtf(pm) + 1e-7f; \
        const float lg   = __log2f(mag); \
        const float mago = pair_swap(mag); \
        const float lgo  = pair_swap(lg); \
        const float d_   = mag - mago; \
        sd2 = fmaf(d_, d_, sd2); \
        sy2 = fmaf(mag, mag, sy2); \
        slg += fabsf(lg - lgo); \
    }

#define FOREMT(M) M(0,1,2) M(1,2,3) M(2,3,4) M(3,4,5) M(4,5,6) \
                  M(5,6,7) M(6,7,8) M(7,8,9) M(8,9,10) M(9,10,11)

#define SLOT(t) { constexpr int TAU = (t); constexpr int PH = (t); FOREMT(EMTB) FORM(UPD_M) }
#define WARM(t) { constexpr int TAU = (t); FORM(WRM_M) }

// one (bin-group, frame-segment, signal) worker. Seg bases B = t0*HH are ALL
// multiples of NN: t0 = 8s (16s for n8), HH = NN/4 -> B = {128s,64s,32s,32s}.
template <int NN, int BSTART, int NB, int EJ0, int EN, int OFF, int LOG2SEGS>
__device__ __forceinline__ void run_group(const float* __restrict__ ps0,
                                          int seg, float& sd2, float& sy2, float& slg)
{
    constexpr int HH = NN / 4;
    constexpr int LNN = (NN == 64) ? 6 : (NN == 32) ? 5 : (NN == 16) ? 4 : 3;
    constexpr int FF = 4096 / NN + 1;           // frames
    constexpr int NQ = FF >> (LOG2SEGS + 2);    // full quad-slots per segment
    const int t0 = (seg * FF) >> LOG2SEGS;
    const int t1 = ((seg + 1) * FF) >> LOG2SEGS;
    const int L  = t1 - t0;
    const int B  = t0 * HH;                     // % NN == 0 by construction
    const float* __restrict__ psb = ps0 + B + (B >> LNN);

    DECLZ
    WARM(0) WARM(1) WARM(2) WARM(3)             // Z = X_{t0} exactly

    int offp = 0;                               // padded offset: off + off>>LNN
#pragma unroll
    for (int q = 0; q < NQ; ++q) {
        SLOT(0) SLOT(1) SLOT(2) SLOT(3)
        offp += NN + 1;                         // off += NN, pad += 1
    }
    if (L > 4 * NQ) { SLOT(0) }                 // rem is 0 or 1 by construction
}

// one resolution per kernel. Block = 256 threads = 4 waves, 4 rows x 2 sigs
// = 8 sequences in LDS. Pad period NN + per-seq phi => exact 2-way banking.
// Staged length SL per kernel = max read index + 1 (proven); RSTR % 32 == 0.
template <int NN, int NGROUPS>
__global__ __launch_bounds__(256, 4)
void sdft_kernel(const float* __restrict__ xg, const float* __restrict__ yg,
                 float* __restrict__ acc /* this resolution: [0],[64],[128] */)
{
    constexpr int LNN  = (NN == 64) ? 6 : (NN == 32) ? 5 : (NN == 16) ? 4 : 3;
    constexpr int SL   = (NN == 64) ? 1104 : (NN == 32) ? 1080 : (NN == 16) ? 1068 : 1064;
    constexpr int RSTR = (NN == 64) ? 1152 : (NN == 32) ? 1152 : (NN == 16) ? 1184 : 1216;
    constexpr int TAIL = SL - 1056;             // staged tail beyond j=1055
    constexpr int PT   = 32 + TAIL;             // pad tasks per sequence

    __shared__ float lds[8][RSTR];              // <=38.9 KB -> 4 blocks/CU
    __shared__ float red[4][3];

    const int tid  = threadIdx.x;
    const int row0 = blockIdx.x << 2;

    // ---- stage central 1024 samples/row/signal as float4 (staged j = 32 + i)
#pragma unroll 1
    for (int task = tid; task < 2048; task += 256) {
        const int q = task & 255, rr = (task >> 8) & 3, sg = task >> 10;
        const float* __restrict__ src = sg ? yg : xg;
        const float4 v = reinterpret_cast<const float4*>(src)[((row0 + rr) << 8) + q];
        const int j = 32 + (q << 2);            // quad never crosses a pad (NN%4==0)
        const int seq = rr * 2 + sg;
        float* dst = &lds[seq][phi_seq<NN>(seq) + KAC(j)];
        dst[0] = __expf(fmaf(v.x, kSigma, kMu));
        dst[1] = __expf(fmaf(v.y, kSigma, kMu));
        dst[2] = __expf(fmaf(v.z, kSigma, kMu));
        dst[3] = __expf(fmaf(v.w, kSigma, kMu));
    }
    // ---- reflect pads (32 left) + tail [1056, SL) (reflect or zero past 1087)
#pragma unroll 1
    for (int task = tid; task < 8 * PT; task += 256) {
        const int p = task % PT, seq = task / PT;
        const int rr = seq >> 1, sg = seq & 1;
        const int j = (p < 32) ? p : (1024 + p);
        float v = 0.f;
        if (j < 1088) {
            const int i = (j < 32) ? (32 - j) : (2078 - j);
            const float* __restrict__ src = sg ? yg : xg;
            v = __expf(fmaf(src[((row0 + rr) << 10) + i], kSigma, kMu));
        }
        lds[seq][phi_seq<NN>(seq) + KAC(j)] = v;
    }
    __syncthreads();

    // ---- wave mapping: group = wid & (NGROUPS-1); remaining wave bits extend seg.
    //      64 lanes = seg(8) x row(4) x sig(2); pair lanes share (seg,row).
    constexpr int GL2 = (NGROUPS == 4) ? 2 : (NGROUPS == 2) ? 1 : 0;
    constexpr int LOG2SEGS = 5 - GL2;           // n64:8, n32:16, n16/n8:32 segments
    const int wid  = tid >> 6, lane = tid & 63;
    const int group  = wid & (NGROUPS - 1);
    const int segblk = wid >> GL2;
    const int seg  = (segblk << 3) | (lane >> 3);
    const int sig  = lane & 1;
    const int seq  = lane & 7;                  // rr*2 + sig
    const float* ps0 = &lds[seq][phi_seq<NN>(seq)];

    float sd2 = 0.f, sy2 = 0.f, slg = 0.f;
    if constexpr (NN == 64) {
        switch (group) {
            case 0:  run_group<64,  0,  9, 0, 8,  0, LOG2SEGS>(ps0, seg, sd2, sy2, slg); break;
            case 1:  run_group<64,  7, 10, 1, 8,  0, LOG2SEGS>(ps0, seg, sd2, sy2, slg); break;
            case 2:  run_group<64, 15, 10, 1, 8,  0, LOG2SEGS>(ps0, seg, sd2, sy2, slg); break;
            default: run_group<64, 23, 10, 1, 9,  0, LOG2SEGS>(ps0, seg, sd2, sy2, slg); break;
        }
    } else if constexpr (NN == 32) {
        if (group == 0) run_group<32,  0,  9, 0, 8, 16, LOG2SEGS>(ps0, seg, sd2, sy2, slg);
        else            run_group<32,  7, 10, 1, 9, 16, LOG2SEGS>(ps0, seg, sd2, sy2, slg);
    } else if constexpr (NN == 16) {
        run_group<16, 0, 9, 0, 9, 24, LOG2SEGS>(ps0, seg, sd2, sy2, slg);
    } else {
        run_group< 8, 0, 5, 0, 5, 28, LOG2SEGS>(ps0, seg, sd2, sy2, slg);
    }

    // ---- reduce: mask sy2 to y-lanes, wave shuffle -> LDS -> 3 atomics/block
    if (!sig) sy2 = 0.f;
#pragma unroll
    for (int o = 32; o > 0; o >>= 1) {
        sd2 += __shfl_down(sd2, o);
        sy2 += __shfl_down(sy2, o);
        slg += __shfl_down(slg, o);
    }
    if (lane == 0) { red[wid][0] = sd2; red[wid][1] = sy2; red[wid][2] = slg; }
    __syncthreads();
    if (tid == 0) {
        atomicAdd(&acc[0],   red[0][0] + red[1][0] + red[2][0] + red[3][0]);
        atomicAdd(&acc[64],  red[0][1] + red[1][1] + red[2][1] + red[3][1]);
        atomicAdd(&acc[128], red[0][2] + red[1][2] + red[2][2] + red[3][2]);
    }
}

__global__ void finalize_kernel(const float* __restrict__ acc, float* __restrict__ out)
{
    if (threadIdx.x == 0 && blockIdx.x == 0) {
        const float nel[4] = {10506240.f, 9474048.f, 8982528.f, 8785920.f};
        float sc = 0.f, mg = 0.f;
#pragma unroll
        for (int r = 0; r < 4; ++r) {
            const float a0 = acc[(r * 3 + 0) * 64];   // 2x sum_d2
            const float a1 = acc[(r * 3 + 1) * 64];   // 1x sum_y2 (masked to y-lanes)
            const float a2 = acc[(r * 3 + 2) * 64];   // 2x sum_|log2 ratio|
            sc += sqrtf(a0 * 0.5f) / (sqrtf(a1) + 1e-8f);
            mg += a2 * 0.34657359028f / nel[r];       // x ln2 / 2
        }
        out[0] = sc * 0.25f;
        out[1] = mg * 0.25f;
    }
}

extern "C" void kernel_launch(void* const* d_in, const int* in_sizes, int n_in,
                              void* d_out, int out_size, void* d_ws, size_t ws_size,
                              hipStream_t stream)
{
    const float* x = (const float*)d_in[0];
    const float* y = (const float*)d_in[1];
    float* out = (float*)d_out;
    float* acc = (float*)d_ws;   // res r base = acc + r*192; r: 0=n8,1=n16,2=n32,3=n64

    hipMemsetAsync(acc, 0, 12 * 64 * sizeof(float), stream);

    sdft_kernel<64, 4><<<1024, 256, 0, stream>>>(x, y, acc + 3 * 192);
    sdft_kernel<32, 2><<<1024, 256, 0, stream>>>(x, y, acc + 2 * 192);
    sdft_kernel<16, 1><<<1024, 256, 0, stream>>>(x, y, acc + 1 * 192);
    sdft_kernel< 8, 1><<<1024, 256, 0, stream>>>(x, y, acc + 0 * 192);

    finalize_kernel<<<1, 64, 0, stream>>>(acc, out);
}